// Round 2
// baseline (281.240 us; speedup 1.0000x reference)
//
#include <hip/hip_runtime.h>

#define TT 4096

typedef unsigned short u16;
typedef unsigned int u32;

typedef short bf16x8 __attribute__((ext_vector_type(8)));
typedef float f32x4 __attribute__((ext_vector_type(4)));

union U8 {
  uint2 q[2];
  bf16x8 v;
  short s[8];
};

static __device__ __forceinline__ u16 f2bf(float f) {
  union { float f; u32 u; } cv;
  cv.f = f;
  u32 r = cv.u + 0x7FFFu + ((cv.u >> 16) & 1u);
  return (u16)(r >> 16);
}
static __device__ __forceinline__ u32 pk2(float a, float b) {
  return (u32)f2bf(a) | ((u32)f2bf(b) << 16);
}

// ---------------------------------------------------------------------------
// Kernel 1: q/k/v projections + LayerNorm, bf16 outputs to ws; x passthrough.
// 256 blocks x 256 threads; block handles 64 rows (lane = row, wave = 16 cols).
// W/bias/gain reads are wave-uniform -> scalar loads; x tile in LDS, +1 pad.
// ---------------------------------------------------------------------------
__global__ __launch_bounds__(256)
void proj_ln(const float* __restrict__ x,
             const float* __restrict__ Wq, const float* __restrict__ bq,
             const float* __restrict__ Wk, const float* __restrict__ bk,
             const float* __restrict__ Wv, const float* __restrict__ bv,
             const float* __restrict__ gq, const float* __restrict__ bgq,
             const float* __restrict__ gk, const float* __restrict__ bgk,
             const float* __restrict__ gv, const float* __restrict__ bgv,
             u16* __restrict__ qo, u16* __restrict__ ko, u16* __restrict__ vto,
             float* __restrict__ out)
{
  __shared__ float xs[64 * 129];
  __shared__ float ps[2][4][64];
  const int tid = threadIdx.x;
  const int w = tid >> 6;
  const int l = tid & 63;
  const int rowbase = blockIdx.x * 64;  // flat row index (b*T + t)

  // stage x tile into LDS + exact fp32 passthrough copy to out[..., 0:128]
#pragma unroll
  for (int it = 0; it < 32; ++it) {
    int flat = it * 256 + tid;
    int r = flat >> 7, c = flat & 127;
    float v = x[(size_t)rowbase * 128 + flat];
    xs[r * 129 + c] = v;
    out[(size_t)(rowbase + r) * 192 + c] = v;
  }
  __syncthreads();

  const int g16 = __builtin_amdgcn_readfirstlane((tid >> 6) << 4);
  const float* Ws[3] = {Wq, Wk, Wv};
  const float* Bs[3] = {bq, bk, bv};
  const float* Gs[3] = {gq, gk, gv};
  const float* Hs[3] = {bgq, bgk, bgv};

  for (int ph = 0; ph < 3; ++ph) {
    const float* W = Ws[ph];
    float acc[16];
#pragma unroll
    for (int j = 0; j < 16; ++j) acc[j] = Bs[ph][g16 + j];
    for (int c = 0; c < 128; ++c) {
      float xv = xs[l * 129 + c];
      const float* wc = W + c * 64 + g16;
#pragma unroll
      for (int j = 0; j < 16; ++j) acc[j] = fmaf(xv, wc[j], acc[j]);
    }
    // LayerNorm over the 64 cols of this row (4 waves hold 16 cols each)
    float s1 = 0.f, s2 = 0.f;
#pragma unroll
    for (int j = 0; j < 16; ++j) { s1 += acc[j]; s2 += acc[j] * acc[j]; }
    ps[0][w][l] = s1;
    ps[1][w][l] = s2;
    __syncthreads();
    float fs = ps[0][0][l] + ps[0][1][l] + ps[0][2][l] + ps[0][3][l];
    float fq = ps[1][0][l] + ps[1][1][l] + ps[1][2][l] + ps[1][3][l];
    __syncthreads();  // ps reused next phase
    float mu = fs * (1.f / 64.f);
    float var = fq * (1.f / 64.f) - mu * mu;
    float rs = rsqrtf(var + 1e-5f);
#pragma unroll
    for (int j = 0; j < 16; ++j)
      acc[j] = (acc[j] - mu) * rs * Gs[ph][g16 + j] + Hs[ph][g16 + j];

    if (ph < 2) {
      u16* dst = (ph == 0 ? qo : ko) + (size_t)(rowbase + l) * 64 + g16;
      uint2 wv;
      wv.x = pk2(acc[0], acc[1]);   wv.y = pk2(acc[2], acc[3]);   *(uint2*)(dst + 0)  = wv;
      wv.x = pk2(acc[4], acc[5]);   wv.y = pk2(acc[6], acc[7]);   *(uint2*)(dst + 4)  = wv;
      wv.x = pk2(acc[8], acc[9]);   wv.y = pk2(acc[10], acc[11]); *(uint2*)(dst + 8)  = wv;
      wv.x = pk2(acc[12], acc[13]); wv.y = pk2(acc[14], acc[15]); *(uint2*)(dst + 12) = wv;
    } else {
      // v stored transposed: vto[b][col][t]  (coalesced: lanes = consecutive t)
      int b = rowbase >> 12;
      int tl = (rowbase & 4095) + l;
#pragma unroll
      for (int j = 0; j < 16; ++j)
        vto[(size_t)(b * 64 + g16 + j) * TT + tl] = f2bf(acc[j]);
    }
  }
}

// ---------------------------------------------------------------------------
// Kernel 2: causal flash attention + output LayerNorm.
// 512 blocks x 128 threads (2 waves). QB=32 q-rows/block (16/wave), SB=64 keys.
// S^T = K*Q^T via mfma_16x16x32_bf16 (swapped operands): lane l holds
// S^T[key=16*t4+4*(l>>4)+reg][qrow=l&15] -> softmax per q-row is in-lane max
// over 16 + shfl_xor(16,32); P regs feed PV A-fragment with no lane movement.
// K tile LDS [key][d], V tile LDS [col][key], both XOR-swizzled ((row&7)<<4).
// ---------------------------------------------------------------------------
__global__ __launch_bounds__(128)
void attn(const u16* __restrict__ qg, const u16* __restrict__ kg,
          const u16* __restrict__ vtg,
          const float* __restrict__ go, const float* __restrict__ bgo,
          float* __restrict__ out)
{
  __shared__ u16 kl[64 * 64];
  __shared__ u16 vl[64 * 64];
  const int bx = blockIdx.x;
  const int tt = (bx < 256) ? bx : (767 - bx);  // pair big+small tiles per CU
  const int b = tt >> 7;
  const int q0 = (tt & 127) * 32;
  const int tid = threadIdx.x;
  const int w = tid >> 6;
  const int l = tid & 63;
  const int l15 = l & 15;
  const int lg = l >> 4;
  const int swzl = (l15 & 7) << 4;

  // Q B-fragments (held in regs for the whole block)
  const int qrow = q0 + 16 * w + l15;
  const u16* qrp = qg + (size_t)(b * TT + qrow) * 64;
  U8 qf[2];
#pragma unroll
  for (int h = 0; h < 2; ++h) {
    qf[h].q[0] = *(const uint2*)(qrp + 32 * h + 4 * lg);
    qf[h].q[1] = *(const uint2*)(qrp + 32 * h + 4 * lg + 16);
  }

  float m_run = -1e30f, l_run = 0.f;
  f32x4 acc[4];
#pragma unroll
  for (int ct = 0; ct < 4; ++ct) acc[ct] = (f32x4){0.f, 0.f, 0.f, 0.f};

  const int nkv = (q0 >> 6) + 1;
  for (int it = 0; it < nkv; ++it) {
    const int kb = it * 64;
    // ---- stage K and V tiles (each thread: 64B of K + 64B of V) ----
    {
      const int key = tid >> 1;          // K: key row   | V: vcol row
      const int dh = (tid & 1) * 32;     // element offset within row
      const u16* ks = kg + (size_t)(b * TT + kb + key) * 64 + dh;
      uint4 d0 = *(const uint4*)(ks + 0);
      uint4 d1 = *(const uint4*)(ks + 8);
      uint4 d2 = *(const uint4*)(ks + 16);
      uint4 d3 = *(const uint4*)(ks + 24);
      const int base = key * 128 + dh * 2;
      const int sw = (key & 7) << 4;
      char* kd = (char*)kl;
      *(uint4*)(kd + ((base + 0) ^ sw)) = d0;
      *(uint4*)(kd + ((base + 16) ^ sw)) = d1;
      *(uint4*)(kd + ((base + 32) ^ sw)) = d2;
      *(uint4*)(kd + ((base + 48) ^ sw)) = d3;
      const u16* vs = vtg + (size_t)(b * 64 + key) * TT + kb + dh;
      uint4 e0 = *(const uint4*)(vs + 0);
      uint4 e1 = *(const uint4*)(vs + 8);
      uint4 e2 = *(const uint4*)(vs + 16);
      uint4 e3 = *(const uint4*)(vs + 24);
      char* vd = (char*)vl;
      *(uint4*)(vd + ((base + 0) ^ sw)) = e0;
      *(uint4*)(vd + ((base + 16) ^ sw)) = e1;
      *(uint4*)(vd + ((base + 32) ^ sw)) = e2;
      *(uint4*)(vd + ((base + 48) ^ sw)) = e3;
    }
    __syncthreads();

    // ---- S^T = K * Q^T ----
    f32x4 st[4];
#pragma unroll
    for (int t4 = 0; t4 < 4; ++t4) {
      const int rbase = (16 * t4 + l15) * 128 + 8 * lg;
      const char* kp = (const char*)kl;
      U8 kf0, kf1;
      kf0.q[0] = *(const uint2*)(kp + ((rbase + 0) ^ swzl));
      kf0.q[1] = *(const uint2*)(kp + ((rbase + 32) ^ swzl));
      kf1.q[0] = *(const uint2*)(kp + ((rbase + 64) ^ swzl));
      kf1.q[1] = *(const uint2*)(kp + ((rbase + 96) ^ swzl));
      f32x4 d = {0.f, 0.f, 0.f, 0.f};
      d = __builtin_amdgcn_mfma_f32_16x16x32_bf16(kf0.v, qf[0].v, d, 0, 0, 0);
      d = __builtin_amdgcn_mfma_f32_16x16x32_bf16(kf1.v, qf[1].v, d, 0, 0, 0);
      st[t4] = d;
    }

    // ---- online softmax (per lane: 16 scores, all for q-row l15) ----
    float sv[16];
    const bool needmask = (kb + 63 > q0 + 16 * w);
#pragma unroll
    for (int t4 = 0; t4 < 4; ++t4) {
#pragma unroll
      for (int r = 0; r < 4; ++r) {
        float s = st[t4][r] * 0.125f;
        if (needmask) {
          int keyidx = kb + 16 * t4 + 4 * lg + r;
          if (keyidx > qrow) s = -1e30f;
        }
        sv[t4 * 4 + r] = s;
      }
    }
    float mt = sv[0];
#pragma unroll
    for (int i = 1; i < 16; ++i) mt = fmaxf(mt, sv[i]);
    mt = fmaxf(mt, __shfl_xor(mt, 16));
    mt = fmaxf(mt, __shfl_xor(mt, 32));
    const float mnew = fmaxf(m_run, mt);
    const float al = __expf(m_run - mnew);
    float p[16];
    float rsum = 0.f;
#pragma unroll
    for (int i = 0; i < 16; ++i) { p[i] = __expf(sv[i] - mnew); rsum += p[i]; }
    rsum += __shfl_xor(rsum, 16);
    rsum += __shfl_xor(rsum, 32);
    l_run = l_run * al + rsum;
    m_run = mnew;
    float ar[4];
#pragma unroll
    for (int r = 0; r < 4; ++r) ar[r] = __shfl(al, 4 * lg + r);
#pragma unroll
    for (int ct = 0; ct < 4; ++ct) {
#pragma unroll
      for (int r = 0; r < 4; ++r) acc[ct][r] *= ar[r];
    }
    U8 pa[2];
#pragma unroll
    for (int u = 0; u < 2; ++u) {
#pragma unroll
      for (int i = 0; i < 8; ++i) pa[u].s[i] = (short)f2bf(p[8 * u + i]);
    }

    // ---- acc += P * V ----
#pragma unroll
    for (int ct = 0; ct < 4; ++ct) {
      const int vb = (16 * ct + l15) * 128 + 8 * lg;
      const char* vp = (const char*)vl;
#pragma unroll
      for (int u = 0; u < 2; ++u) {
        U8 vf;
        vf.q[0] = *(const uint2*)(vp + ((vb + 64 * u + 0) ^ swzl));
        vf.q[1] = *(const uint2*)(vp + ((vb + 64 * u + 32) ^ swzl));
        acc[ct] = __builtin_amdgcn_mfma_f32_16x16x32_bf16(pa[u].v, vf.v, acc[ct], 0, 0, 0);
      }
    }
    __syncthreads();
  }

  // ---- epilogue: 1/l normalize, LayerNorm over 64 v-cols, store fp32 ----
  float linv[4];
#pragma unroll
  for (int r = 0; r < 4; ++r) linv[r] = 1.f / __shfl(l_run, 4 * lg + r);
  float o[4][4];
#pragma unroll
  for (int ct = 0; ct < 4; ++ct) {
#pragma unroll
    for (int r = 0; r < 4; ++r) o[ct][r] = acc[ct][r] * linv[r];
  }
  float s1[4], s2[4];
#pragma unroll
  for (int r = 0; r < 4; ++r) {
    s1[r] = o[0][r] + o[1][r] + o[2][r] + o[3][r];
    s2[r] = o[0][r] * o[0][r] + o[1][r] * o[1][r] + o[2][r] * o[2][r] + o[3][r] * o[3][r];
#pragma unroll
    for (int d = 1; d < 16; d <<= 1) {
      s1[r] += __shfl_xor(s1[r], d);
      s2[r] += __shfl_xor(s2[r], d);
    }
  }
  float gov[4], bgv2[4];
#pragma unroll
  for (int ct = 0; ct < 4; ++ct) {
    gov[ct] = go[16 * ct + l15];
    bgv2[ct] = bgo[16 * ct + l15];
  }
#pragma unroll
  for (int r = 0; r < 4; ++r) {
    float mu = s1[r] * (1.f / 64.f);
    float var = s2[r] * (1.f / 64.f) - mu * mu;
    float rs = rsqrtf(var + 1e-5f);
    int row = q0 + 16 * w + 4 * lg + r;
    float* op = out + (size_t)(b * TT + row) * 192 + 128;
#pragma unroll
    for (int ct = 0; ct < 4; ++ct)
      op[16 * ct + l15] = (o[ct][r] - mu) * rs * gov[ct] + bgv2[ct];
  }
}

extern "C" void kernel_launch(void* const* d_in, const int* in_sizes, int n_in,
                              void* d_out, int out_size, void* d_ws, size_t ws_size,
                              hipStream_t stream) {
  (void)in_sizes; (void)n_in; (void)out_size; (void)ws_size;
  const float* x   = (const float*)d_in[0];
  const float* Wq  = (const float*)d_in[1];
  const float* bq  = (const float*)d_in[2];
  const float* Wk  = (const float*)d_in[3];
  const float* bk  = (const float*)d_in[4];
  const float* Wv  = (const float*)d_in[5];
  const float* bv  = (const float*)d_in[6];
  const float* gq  = (const float*)d_in[7];
  const float* bgq = (const float*)d_in[8];
  const float* gk  = (const float*)d_in[9];
  const float* bgk = (const float*)d_in[10];
  const float* gv  = (const float*)d_in[11];
  const float* bgv = (const float*)d_in[12];
  const float* go  = (const float*)d_in[13];
  const float* bgo = (const float*)d_in[14];
  float* out = (float*)d_out;

  u16* qws  = (u16*)d_ws;                 // 4*4096*64 bf16 = 2 MB
  u16* kws  = qws + 4 * 4096 * 64;        // 2 MB
  u16* vtws = kws + 4 * 4096 * 64;        // 2 MB, stored [b][col][t]

  proj_ln<<<256, 256, 0, stream>>>(x, Wq, bq, Wk, bk, Wv, bv,
                                   gq, bgq, gk, bgk, gv, bgv,
                                   qws, kws, vtws, out);
  attn<<<512, 128, 0, stream>>>(qws, kws, vtws, go, bgo, out);
}

// Round 3
// 85.732 us; speedup vs baseline: 3.2804x; 3.2804x over previous
//
#include <hip/hip_runtime.h>

#define TT 4096

typedef unsigned short u16;
typedef unsigned int u32;

typedef short bf16x8 __attribute__((ext_vector_type(8)));
typedef float f32x4 __attribute__((ext_vector_type(4)));

union U8 {
  uint2 q[2];
  uint4 u4;
  bf16x8 v;
  short s[8];
};

static __device__ __forceinline__ u16 f2bf(float f) {
  union { float f; u32 u; } cv;
  cv.f = f;
  u32 r = cv.u + 0x7FFFu + ((cv.u >> 16) & 1u);
  return (u16)(r >> 16);
}
static __device__ __forceinline__ u32 pk2(float a, float b) {
  return (u32)f2bf(a) | ((u32)f2bf(b) << 16);
}

// ---------------------------------------------------------------------------
// Kernel 0: pack W{q,k,v} (fp32 [128][64]) into MFMA B-fragment layout, bf16.
// Layout: frag g=(p*16+s*4+nt), lane l: 8 contiguous bf16 at wf[(g*64+l)*8].
// Slot j of lane l holds W[32s + (j<4 ? 4*lg+j : 16+4*lg+j-4)][l15+16*nt].
// ---------------------------------------------------------------------------
__global__ __launch_bounds__(64)
void wpack(const float* __restrict__ Wq, const float* __restrict__ Wk,
           const float* __restrict__ Wv, u16* __restrict__ wf)
{
  const int g = blockIdx.x;              // 0..47
  const int p = g >> 4, s = (g >> 2) & 3, nt = g & 3;
  const int l = threadIdx.x, lg = l >> 4, l15 = l & 15;
  const float* W = (p == 0) ? Wq : (p == 1) ? Wk : Wv;
  const int n = l15 + 16 * nt;
  U8 o;
#pragma unroll
  for (int j = 0; j < 8; ++j) {
    int k = 32 * s + ((j < 4) ? (4 * lg + j) : (16 + 4 * lg + (j - 4)));
    o.s[j] = (short)f2bf(W[k * 64 + n]);
  }
  *(uint4*)(wf + (size_t)(g * 64 + l) * 8) = o.u4;
}

// ---------------------------------------------------------------------------
// Kernel 1: projections via MFMA + LayerNorm. 768 blocks x 256 thr (4 waves).
// Block = (tile of 64 rows) x (one projection p). Wave = 16 rows x 64 cols,
// K=128 as 4 MFMA k-steps. x staged bf16 in XOR-swizzled LDS. p==0 blocks
// also do the exact fp32 x passthrough to out[...,0:128].
// XCD map: same tile's 3 p-blocks land on one XCD (x re-read hits L2).
// ---------------------------------------------------------------------------
__global__ __launch_bounds__(256)
void proj_mfma(const float* __restrict__ x, const u16* __restrict__ wf,
               const float* __restrict__ bq, const float* __restrict__ bk,
               const float* __restrict__ bv,
               const float* __restrict__ gq, const float* __restrict__ bgq,
               const float* __restrict__ gk, const float* __restrict__ bgk,
               const float* __restrict__ gv, const float* __restrict__ bgv,
               u16* __restrict__ qo, u16* __restrict__ ko, u16* __restrict__ vto,
               float* __restrict__ out)
{
  __shared__ u16 xs[64 * 128];           // 16 KB, swizzled
  const int bx = blockIdx.x;
  const int xcd = bx & 7, i = bx >> 3;
  const int tile = xcd * 32 + (i & 31);  // 0..255
  const int p = i >> 5;                  // 0..2
  const int rowbase = tile * 64;
  const int t = threadIdx.x;

  // ---- stage x tile as bf16 (swizzled) + fp32 passthrough (p==0) ----
  {
    const int row = t >> 2, seg = t & 3;
    const float4* src = (const float4*)(x + (size_t)(rowbase + row) * 128 + seg * 32);
    float4 f[8];
#pragma unroll
    for (int q = 0; q < 8; ++q) f[q] = src[q];
    if (p == 0) {
      float4* dst = (float4*)(out + (size_t)(rowbase + row) * 192 + seg * 32);
#pragma unroll
      for (int q = 0; q < 8; ++q) dst[q] = f[q];
    }
    const int base = row * 256 + seg * 64;
    const int swz = (row & 7) << 4;
    char* xb = (char*)xs;
#pragma unroll
    for (int q = 0; q < 4; ++q) {
      uint4 u;
      u.x = pk2(f[2 * q].x, f[2 * q].y);
      u.y = pk2(f[2 * q].z, f[2 * q].w);
      u.z = pk2(f[2 * q + 1].x, f[2 * q + 1].y);
      u.w = pk2(f[2 * q + 1].z, f[2 * q + 1].w);
      *(uint4*)(xb + ((base + 16 * q) ^ swz)) = u;
    }
  }

  // ---- load B fragments (coalesced b128 from packed W) ----
  const int w = t >> 6, l = t & 63, lg = l >> 4, l15 = l & 15;
  U8 bfr[4][4];
  const u16* wp = wf + (size_t)p * (16 * 64 * 8);
#pragma unroll
  for (int s = 0; s < 4; ++s)
#pragma unroll
    for (int nt = 0; nt < 4; ++nt)
      bfr[s][nt].u4 = *(const uint4*)(wp + ((s * 4 + nt) * 64 + l) * 8);

  __syncthreads();

  // ---- MFMA: 16 rows x 64 cols, K=128 ----
  f32x4 acc[4];
#pragma unroll
  for (int nt = 0; nt < 4; ++nt) acc[nt] = (f32x4){0.f, 0.f, 0.f, 0.f};
  const int abase = (16 * w + l15) * 256;
  const int aswz = (l15 & 7) << 4;
  const char* xb = (const char*)xs;
#pragma unroll
  for (int s = 0; s < 4; ++s) {
    U8 af;
    af.q[0] = *(const uint2*)(xb + ((abase + s * 64 + 8 * lg) ^ aswz));
    af.q[1] = *(const uint2*)(xb + ((abase + s * 64 + 8 * lg + 32) ^ aswz));
#pragma unroll
    for (int nt = 0; nt < 4; ++nt)
      acc[nt] = __builtin_amdgcn_mfma_f32_16x16x32_bf16(af.v, bfr[s][nt].v, acc[nt], 0, 0, 0);
  }

  // ---- bias + LayerNorm + store ----
  const float* bb = (p == 0) ? bq : (p == 1) ? bk : bv;
  const float* gg = (p == 0) ? gq : (p == 1) ? gk : gv;
  const float* hh = (p == 0) ? bgq : (p == 1) ? bgk : bgv;
  float bcol[4], gcol[4], hcol[4];
#pragma unroll
  for (int nt = 0; nt < 4; ++nt) {
    int col = l15 + 16 * nt;
    bcol[nt] = bb[col]; gcol[nt] = gg[col]; hcol[nt] = hh[col];
  }
  float vals[4][4];  // [nt][r]
#pragma unroll
  for (int nt = 0; nt < 4; ++nt)
#pragma unroll
    for (int r = 0; r < 4; ++r) vals[nt][r] = acc[nt][r] + bcol[nt];

  float s1[4], s2[4];
#pragma unroll
  for (int r = 0; r < 4; ++r) {
    s1[r] = vals[0][r] + vals[1][r] + vals[2][r] + vals[3][r];
    s2[r] = vals[0][r] * vals[0][r] + vals[1][r] * vals[1][r]
          + vals[2][r] * vals[2][r] + vals[3][r] * vals[3][r];
#pragma unroll
    for (int d = 1; d < 16; d <<= 1) {
      s1[r] += __shfl_xor(s1[r], d);
      s2[r] += __shfl_xor(s2[r], d);
    }
  }

  if (p < 2) {
    u16* dst = (p == 0) ? qo : ko;
#pragma unroll
    for (int r = 0; r < 4; ++r) {
      float mu = s1[r] * (1.f / 64.f);
      float var = s2[r] * (1.f / 64.f) - mu * mu;
      float rs = rsqrtf(var + 1e-5f);
      int grow = rowbase + 16 * w + 4 * lg + r;
#pragma unroll
      for (int nt = 0; nt < 4; ++nt)
        dst[(size_t)grow * 64 + l15 + 16 * nt] =
            f2bf((vals[nt][r] - mu) * rs * gcol[nt] + hcol[nt]);
    }
  } else {
    const int b = rowbase >> 12;
    const int tl0 = (rowbase & 4095) + 16 * w + 4 * lg;
#pragma unroll
    for (int r = 0; r < 4; ++r) {
      float mu = s1[r] * (1.f / 64.f);
      float var = s2[r] * (1.f / 64.f) - mu * mu;
      float rs = rsqrtf(var + 1e-5f);
#pragma unroll
      for (int nt = 0; nt < 4; ++nt)
        vto[(size_t)(b * 64 + l15 + 16 * nt) * TT + tl0 + r] =
            f2bf((vals[nt][r] - mu) * rs * gcol[nt] + hcol[nt]);
    }
  }
}

// ---------------------------------------------------------------------------
// Kernel 2a: causal flash attention, 2-way key-split partials.
// 512 blocks x 256 thr (4 waves). QB=64 rows (16/wave), SB=64 keys.
// XCD map: batch pinned to an XCD pair (K/V L2-resident); halves reverse-
// paired so each CU's two blocks sum to ~constant work.
// Writes pre-normalized acc + per-row (m,l) partials.
// ---------------------------------------------------------------------------
__global__ __launch_bounds__(256)
void attn_split(const u16* __restrict__ qg, const u16* __restrict__ kg,
                const u16* __restrict__ vtg,
                float* __restrict__ mP, float* __restrict__ lP,
                float* __restrict__ aP)
{
  __shared__ u16 kl[64 * 64];
  __shared__ u16 vl[64 * 64];
  const int bx = blockIdx.x;
  const int xcd = bx & 7, b = xcd >> 1, e = xcd & 1;
  const int s = bx >> 3;                  // 0..63
  const int h = s >> 5;                   // half
  const int pp = s & 31;
  const int ql = h ? (31 - pp) : pp;
  const int qtile = 2 * ql + e;           // 0..63
  const int q0 = qtile * 64;
  const int tileid = b * 64 + qtile;      // 0..255
  const int n = qtile + 1, nh = n >> 1;
  const int it0 = h ? nh : 0, it1 = h ? n : nh;

  const int t = threadIdx.x;
  const int w = t >> 6, l = t & 63;
  const int l15 = l & 15, lg = l >> 4;
  const int swzl = (l15 & 7) << 4;

  const int qrow = q0 + 16 * w + l15;
  const u16* qrp = qg + (size_t)(b * TT + qrow) * 64;
  U8 qf[2];
#pragma unroll
  for (int hh = 0; hh < 2; ++hh) {
    qf[hh].q[0] = *(const uint2*)(qrp + 32 * hh + 4 * lg);
    qf[hh].q[1] = *(const uint2*)(qrp + 32 * hh + 4 * lg + 16);
  }

  float m_run = -1e30f, l_run = 0.f;
  f32x4 acc[4];
#pragma unroll
  for (int ct = 0; ct < 4; ++ct) acc[ct] = (f32x4){0.f, 0.f, 0.f, 0.f};

  for (int it = it0; it < it1; ++it) {
    const int kb = it * 64;
    // ---- stage K and V tiles (4 thr/row, 32 B each) ----
    {
      const int key = t >> 2;
      const int part = t & 3;
      const u16* ks = kg + (size_t)(b * TT + kb + key) * 64 + part * 16;
      uint4 d0 = ((const uint4*)ks)[0];
      uint4 d1 = ((const uint4*)ks)[1];
      const int base = key * 128 + part * 32;
      const int sw = (key & 7) << 4;
      char* kd = (char*)kl;
      *(uint4*)(kd + ((base + 0) ^ sw)) = d0;
      *(uint4*)(kd + ((base + 16) ^ sw)) = d1;
      const u16* vs = vtg + (size_t)(b * 64 + key) * TT + kb + part * 16;
      uint4 e0 = ((const uint4*)vs)[0];
      uint4 e1 = ((const uint4*)vs)[1];
      char* vd = (char*)vl;
      *(uint4*)(vd + ((base + 0) ^ sw)) = e0;
      *(uint4*)(vd + ((base + 16) ^ sw)) = e1;
    }
    __syncthreads();

    // ---- S^T = K * Q^T ----
    f32x4 st[4];
#pragma unroll
    for (int t4 = 0; t4 < 4; ++t4) {
      const int rbase = (16 * t4 + l15) * 128 + 8 * lg;
      const char* kp = (const char*)kl;
      U8 kf0, kf1;
      kf0.q[0] = *(const uint2*)(kp + ((rbase + 0) ^ swzl));
      kf0.q[1] = *(const uint2*)(kp + ((rbase + 32) ^ swzl));
      kf1.q[0] = *(const uint2*)(kp + ((rbase + 64) ^ swzl));
      kf1.q[1] = *(const uint2*)(kp + ((rbase + 96) ^ swzl));
      f32x4 d = {0.f, 0.f, 0.f, 0.f};
      d = __builtin_amdgcn_mfma_f32_16x16x32_bf16(kf0.v, qf[0].v, d, 0, 0, 0);
      d = __builtin_amdgcn_mfma_f32_16x16x32_bf16(kf1.v, qf[1].v, d, 0, 0, 0);
      st[t4] = d;
    }

    // ---- online softmax ----
    float sv[16];
    const bool needmask = (kb + 63 > q0 + 16 * w);
#pragma unroll
    for (int t4 = 0; t4 < 4; ++t4) {
#pragma unroll
      for (int r = 0; r < 4; ++r) {
        float sc = st[t4][r] * 0.125f;
        if (needmask) {
          int keyidx = kb + 16 * t4 + 4 * lg + r;
          if (keyidx > qrow) sc = -1e30f;
        }
        sv[t4 * 4 + r] = sc;
      }
    }
    float mt = sv[0];
#pragma unroll
    for (int i = 1; i < 16; ++i) mt = fmaxf(mt, sv[i]);
    mt = fmaxf(mt, __shfl_xor(mt, 16));
    mt = fmaxf(mt, __shfl_xor(mt, 32));
    const float mnew = fmaxf(m_run, mt);
    const float al = __expf(m_run - mnew);
    float pv[16];
    float rsum = 0.f;
#pragma unroll
    for (int i = 0; i < 16; ++i) { pv[i] = __expf(sv[i] - mnew); rsum += pv[i]; }
    rsum += __shfl_xor(rsum, 16);
    rsum += __shfl_xor(rsum, 32);
    l_run = l_run * al + rsum;
    m_run = mnew;
    float ar[4];
#pragma unroll
    for (int r = 0; r < 4; ++r) ar[r] = __shfl(al, 4 * lg + r);
#pragma unroll
    for (int ct = 0; ct < 4; ++ct) {
#pragma unroll
      for (int r = 0; r < 4; ++r) acc[ct][r] *= ar[r];
    }
    U8 pa[2];
#pragma unroll
    for (int u = 0; u < 2; ++u) {
#pragma unroll
      for (int i = 0; i < 8; ++i) pa[u].s[i] = (short)f2bf(pv[8 * u + i]);
    }

    // ---- acc += P * V ----
#pragma unroll
    for (int ct = 0; ct < 4; ++ct) {
      const int vb = (16 * ct + l15) * 128 + 8 * lg;
      const char* vp = (const char*)vl;
#pragma unroll
      for (int u = 0; u < 2; ++u) {
        U8 vf;
        vf.q[0] = *(const uint2*)(vp + ((vb + 64 * u + 0) ^ swzl));
        vf.q[1] = *(const uint2*)(vp + ((vb + 64 * u + 32) ^ swzl));
        acc[ct] = __builtin_amdgcn_mfma_f32_16x16x32_bf16(pa[u].v, vf.v, acc[ct], 0, 0, 0);
      }
    }
    __syncthreads();
  }

  // ---- write partials ----
  if (lg == 0) {
    mP[(size_t)tileid * 128 + h * 64 + 16 * w + l15] = m_run;
    lP[(size_t)tileid * 128 + h * 64 + 16 * w + l15] = l_run;
  }
#pragma unroll
  for (int ct = 0; ct < 4; ++ct) {
#pragma unroll
    for (int r = 0; r < 4; ++r) {
      int rin = 16 * w + 4 * lg + r;
      aP[((size_t)(tileid * 2 + h) * 64 + rin) * 64 + l15 + 16 * ct] = acc[ct][r];
    }
  }
}

// ---------------------------------------------------------------------------
// Kernel 2b: merge the two key-halves + output LayerNorm. Wave = one row.
// ---------------------------------------------------------------------------
__global__ __launch_bounds__(256)
void attn_merge(const float* __restrict__ mP, const float* __restrict__ lP,
                const float* __restrict__ aP,
                const float* __restrict__ go, const float* __restrict__ bgo,
                float* __restrict__ out)
{
  const int t = threadIdx.x;
  const int w = t >> 6, c = t & 63;
  const int row = blockIdx.x * 4 + w;       // 0..16383
  const int tid2 = row >> 6, rin = row & 63;
  float m0 = mP[(size_t)tid2 * 128 + rin];
  float m1 = mP[(size_t)tid2 * 128 + 64 + rin];
  float l0 = lP[(size_t)tid2 * 128 + rin];
  float l1 = lP[(size_t)tid2 * 128 + 64 + rin];
  float a0 = aP[((size_t)(tid2 * 2) * 64 + rin) * 64 + c];
  float a1 = aP[((size_t)(tid2 * 2 + 1) * 64 + rin) * 64 + c];
  float ms = fmaxf(m0, m1);
  float w0 = __expf(m0 - ms), w1 = __expf(m1 - ms);
  float L = l0 * w0 + l1 * w1;
  float o = (a0 * w0 + a1 * w1) / L;
  float s1 = o, s2 = o * o;
#pragma unroll
  for (int d = 1; d < 64; d <<= 1) {
    s1 += __shfl_xor(s1, d);
    s2 += __shfl_xor(s2, d);
  }
  float mu = s1 * (1.f / 64.f);
  float var = s2 * (1.f / 64.f) - mu * mu;
  float rs = rsqrtf(var + 1e-5f);
  out[(size_t)row * 192 + 128 + c] = (o - mu) * rs * go[c] + bgo[c];
}

// ---------------------------------------------------------------------------
// Kernel 2 fallback (ws too small for split partials): round-2 proven attn.
// 512 blocks x 128 thr (2 waves), QB=32, inline LN epilogue.
// ---------------------------------------------------------------------------
__global__ __launch_bounds__(128)
void attn1(const u16* __restrict__ qg, const u16* __restrict__ kg,
           const u16* __restrict__ vtg,
           const float* __restrict__ go, const float* __restrict__ bgo,
           float* __restrict__ out)
{
  __shared__ u16 kl[64 * 64];
  __shared__ u16 vl[64 * 64];
  const int bx = blockIdx.x;
  const int tt = (bx < 256) ? bx : (767 - bx);
  const int b = tt >> 7;
  const int q0 = (tt & 127) * 32;
  const int tid = threadIdx.x;
  const int w = tid >> 6;
  const int l = tid & 63;
  const int l15 = l & 15;
  const int lg = l >> 4;
  const int swzl = (l15 & 7) << 4;

  const int qrow = q0 + 16 * w + l15;
  const u16* qrp = qg + (size_t)(b * TT + qrow) * 64;
  U8 qf[2];
#pragma unroll
  for (int h = 0; h < 2; ++h) {
    qf[h].q[0] = *(const uint2*)(qrp + 32 * h + 4 * lg);
    qf[h].q[1] = *(const uint2*)(qrp + 32 * h + 4 * lg + 16);
  }

  float m_run = -1e30f, l_run = 0.f;
  f32x4 acc[4];
#pragma unroll
  for (int ct = 0; ct < 4; ++ct) acc[ct] = (f32x4){0.f, 0.f, 0.f, 0.f};

  const int nkv = (q0 >> 6) + 1;
  for (int it = 0; it < nkv; ++it) {
    const int kb = it * 64;
    {
      const int key = tid >> 1;
      const int dh = (tid & 1) * 32;
      const u16* ks = kg + (size_t)(b * TT + kb + key) * 64 + dh;
      uint4 d0 = *(const uint4*)(ks + 0);
      uint4 d1 = *(const uint4*)(ks + 8);
      uint4 d2 = *(const uint4*)(ks + 16);
      uint4 d3 = *(const uint4*)(ks + 24);
      const int base = key * 128 + dh * 2;
      const int sw = (key & 7) << 4;
      char* kd = (char*)kl;
      *(uint4*)(kd + ((base + 0) ^ sw)) = d0;
      *(uint4*)(kd + ((base + 16) ^ sw)) = d1;
      *(uint4*)(kd + ((base + 32) ^ sw)) = d2;
      *(uint4*)(kd + ((base + 48) ^ sw)) = d3;
      const u16* vs = vtg + (size_t)(b * 64 + key) * TT + kb + dh;
      uint4 e0 = *(const uint4*)(vs + 0);
      uint4 e1 = *(const uint4*)(vs + 8);
      uint4 e2 = *(const uint4*)(vs + 16);
      uint4 e3 = *(const uint4*)(vs + 24);
      char* vd = (char*)vl;
      *(uint4*)(vd + ((base + 0) ^ sw)) = e0;
      *(uint4*)(vd + ((base + 16) ^ sw)) = e1;
      *(uint4*)(vd + ((base + 32) ^ sw)) = e2;
      *(uint4*)(vd + ((base + 48) ^ sw)) = e3;
    }
    __syncthreads();

    f32x4 st[4];
#pragma unroll
    for (int t4 = 0; t4 < 4; ++t4) {
      const int rbase = (16 * t4 + l15) * 128 + 8 * lg;
      const char* kp = (const char*)kl;
      U8 kf0, kf1;
      kf0.q[0] = *(const uint2*)(kp + ((rbase + 0) ^ swzl));
      kf0.q[1] = *(const uint2*)(kp + ((rbase + 32) ^ swzl));
      kf1.q[0] = *(const uint2*)(kp + ((rbase + 64) ^ swzl));
      kf1.q[1] = *(const uint2*)(kp + ((rbase + 96) ^ swzl));
      f32x4 d = {0.f, 0.f, 0.f, 0.f};
      d = __builtin_amdgcn_mfma_f32_16x16x32_bf16(kf0.v, qf[0].v, d, 0, 0, 0);
      d = __builtin_amdgcn_mfma_f32_16x16x32_bf16(kf1.v, qf[1].v, d, 0, 0, 0);
      st[t4] = d;
    }

    float sv[16];
    const bool needmask = (kb + 63 > q0 + 16 * w);
#pragma unroll
    for (int t4 = 0; t4 < 4; ++t4) {
#pragma unroll
      for (int r = 0; r < 4; ++r) {
        float sc = st[t4][r] * 0.125f;
        if (needmask) {
          int keyidx = kb + 16 * t4 + 4 * lg + r;
          if (keyidx > qrow) sc = -1e30f;
        }
        sv[t4 * 4 + r] = sc;
      }
    }
    float mt = sv[0];
#pragma unroll
    for (int i = 1; i < 16; ++i) mt = fmaxf(mt, sv[i]);
    mt = fmaxf(mt, __shfl_xor(mt, 16));
    mt = fmaxf(mt, __shfl_xor(mt, 32));
    const float mnew = fmaxf(m_run, mt);
    const float al = __expf(m_run - mnew);
    float p[16];
    float rsum = 0.f;
#pragma unroll
    for (int i = 0; i < 16; ++i) { p[i] = __expf(sv[i] - mnew); rsum += p[i]; }
    rsum += __shfl_xor(rsum, 16);
    rsum += __shfl_xor(rsum, 32);
    l_run = l_run * al + rsum;
    m_run = mnew;
    float ar[4];
#pragma unroll
    for (int r = 0; r < 4; ++r) ar[r] = __shfl(al, 4 * lg + r);
#pragma unroll
    for (int ct = 0; ct < 4; ++ct) {
#pragma unroll
      for (int r = 0; r < 4; ++r) acc[ct][r] *= ar[r];
    }
    U8 pa[2];
#pragma unroll
    for (int u = 0; u < 2; ++u) {
#pragma unroll
      for (int i = 0; i < 8; ++i) pa[u].s[i] = (short)f2bf(p[8 * u + i]);
    }

#pragma unroll
    for (int ct = 0; ct < 4; ++ct) {
      const int vb = (16 * ct + l15) * 128 + 8 * lg;
      const char* vp = (const char*)vl;
#pragma unroll
      for (int u = 0; u < 2; ++u) {
        U8 vf;
        vf.q[0] = *(const uint2*)(vp + ((vb + 64 * u + 0) ^ swzl));
        vf.q[1] = *(const uint2*)(vp + ((vb + 64 * u + 32) ^ swzl));
        acc[ct] = __builtin_amdgcn_mfma_f32_16x16x32_bf16(pa[u].v, vf.v, acc[ct], 0, 0, 0);
      }
    }
    __syncthreads();
  }

  float linv[4];
#pragma unroll
  for (int r = 0; r < 4; ++r) linv[r] = 1.f / __shfl(l_run, 4 * lg + r);
  float o[4][4];
#pragma unroll
  for (int ct = 0; ct < 4; ++ct) {
#pragma unroll
    for (int r = 0; r < 4; ++r) o[ct][r] = acc[ct][r] * linv[r];
  }
  float s1[4], s2[4];
#pragma unroll
  for (int r = 0; r < 4; ++r) {
    s1[r] = o[0][r] + o[1][r] + o[2][r] + o[3][r];
    s2[r] = o[0][r] * o[0][r] + o[1][r] * o[1][r] + o[2][r] * o[2][r] + o[3][r] * o[3][r];
#pragma unroll
    for (int d = 1; d < 16; d <<= 1) {
      s1[r] += __shfl_xor(s1[r], d);
      s2[r] += __shfl_xor(s2[r], d);
    }
  }
  float gov[4], bgv2[4];
#pragma unroll
  for (int ct = 0; ct < 4; ++ct) {
    gov[ct] = go[16 * ct + l15];
    bgv2[ct] = bgo[16 * ct + l15];
  }
#pragma unroll
  for (int r = 0; r < 4; ++r) {
    float mu = s1[r] * (1.f / 64.f);
    float var = s2[r] * (1.f / 64.f) - mu * mu;
    float rs = rsqrtf(var + 1e-5f);
    int row = q0 + 16 * w + 4 * lg + r;
    float* op = out + (size_t)(b * TT + row) * 192 + 128;
#pragma unroll
    for (int ct = 0; ct < 4; ++ct)
      op[16 * ct + l15] = (o[ct][r] - mu) * rs * gov[ct] + bgv2[ct];
  }
}

extern "C" void kernel_launch(void* const* d_in, const int* in_sizes, int n_in,
                              void* d_out, int out_size, void* d_ws, size_t ws_size,
                              hipStream_t stream) {
  (void)in_sizes; (void)n_in; (void)out_size;
  const float* x   = (const float*)d_in[0];
  const float* Wq  = (const float*)d_in[1];
  const float* bq  = (const float*)d_in[2];
  const float* Wk  = (const float*)d_in[3];
  const float* bk  = (const float*)d_in[4];
  const float* Wv  = (const float*)d_in[5];
  const float* bv  = (const float*)d_in[6];
  const float* gq  = (const float*)d_in[7];
  const float* bgq = (const float*)d_in[8];
  const float* gk  = (const float*)d_in[9];
  const float* bgk = (const float*)d_in[10];
  const float* gv  = (const float*)d_in[11];
  const float* bgv = (const float*)d_in[12];
  const float* go  = (const float*)d_in[13];
  const float* bgo = (const float*)d_in[14];
  float* out = (float*)d_out;

  // ws layout (bytes):
  //   0        q      (2 MB bf16 [b*T][64])
  //   2 MB     k      (2 MB)
  //   4 MB     vt     (2 MB, [b][col][T])
  //   6 MB     Wfrag  (48 KB packed B-fragments, 64 KB slot)
  //   +64 KB   mP     (128 KB)   \
  //   +128 KB  lP     (128 KB)    > split-K partials (only if ws fits)
  //   +128 KB  aP     (8 MB)     /
  char* wsb = (char*)d_ws;
  u16* qws  = (u16*)wsb;
  u16* kws  = (u16*)(wsb + (2u << 20));
  u16* vtws = (u16*)(wsb + (4u << 20));
  u16* wfr  = (u16*)(wsb + (6u << 20));
  const size_t OFF_MP = (6u << 20) + 65536;
  const size_t OFF_LP = OFF_MP + 131072;
  const size_t OFF_AP = OFF_LP + 131072;
  const size_t NEED_SPLIT = OFF_AP + (8u << 20);   // 15,007,744 B
  float* mP = (float*)(wsb + OFF_MP);
  float* lP = (float*)(wsb + OFF_LP);
  float* aP = (float*)(wsb + OFF_AP);

  wpack<<<48, 64, 0, stream>>>(Wq, Wk, Wv, wfr);
  proj_mfma<<<768, 256, 0, stream>>>(x, wfr, bq, bk, bv,
                                     gq, bgq, gk, bgk, gv, bgv,
                                     qws, kws, vtws, out);
  if (ws_size >= NEED_SPLIT) {
    attn_split<<<512, 256, 0, stream>>>(qws, kws, vtws, mP, lP, aP);
    attn_merge<<<4096, 256, 0, stream>>>(mP, lP, aP, go, bgo, out);
  } else {
    attn1<<<512, 128, 0, stream>>>(qws, kws, vtws, go, bgo, out);
  }
}

// Round 4
// 72.405 us; speedup vs baseline: 3.8843x; 1.1841x over previous
//
#include <hip/hip_runtime.h>

#define TT 4096

typedef unsigned short u16;
typedef unsigned int u32;

typedef short bf16x8 __attribute__((ext_vector_type(8)));
typedef float f32x4 __attribute__((ext_vector_type(4)));

union U8 {
  uint2 q[2];
  uint4 u4;
  bf16x8 v;
  short s[8];
};

static __device__ __forceinline__ u16 f2bf(float f) {
  union { float f; u32 u; } cv;
  cv.f = f;
  u32 r = cv.u + 0x7FFFu + ((cv.u >> 16) & 1u);
  return (u16)(r >> 16);
}
static __device__ __forceinline__ u32 pk2(float a, float b) {
  return (u32)f2bf(a) | ((u32)f2bf(b) << 16);
}
static __device__ __forceinline__ float bf2f(u16 h) {
  union { u32 u; float f; } cv;
  cv.u = ((u32)h) << 16;
  return cv.f;
}

// ---------------------------------------------------------------------------
// Kernel 0: pack W{q,k,v} (fp32 [128][64]) into MFMA B-fragment layout, bf16.
// ---------------------------------------------------------------------------
__global__ __launch_bounds__(64)
void wpack(const float* __restrict__ Wq, const float* __restrict__ Wk,
           const float* __restrict__ Wv, u16* __restrict__ wf)
{
  const int g = blockIdx.x;              // 0..47
  const int p = g >> 4, s = (g >> 2) & 3, nt = g & 3;
  const int l = threadIdx.x, lg = l >> 4, l15 = l & 15;
  const float* W = (p == 0) ? Wq : (p == 1) ? Wk : Wv;
  const int n = l15 + 16 * nt;
  U8 o;
#pragma unroll
  for (int j = 0; j < 8; ++j) {
    int k = 32 * s + ((j < 4) ? (4 * lg + j) : (16 + 4 * lg + (j - 4)));
    o.s[j] = (short)f2bf(W[k * 64 + n]);
  }
  *(uint4*)(wf + (size_t)(g * 64 + l) * 8) = o.u4;
}

// ---------------------------------------------------------------------------
// Kernel 1: projections via MFMA + LayerNorm. 768 blocks x 256 thr (4 waves).
// x passthrough split: p==0 copies cols 0-63, p==1 copies cols 64-127.
// ---------------------------------------------------------------------------
__global__ __launch_bounds__(256)
void proj_mfma(const float* __restrict__ x, const u16* __restrict__ wf,
               const float* __restrict__ bq, const float* __restrict__ bk,
               const float* __restrict__ bv,
               const float* __restrict__ gq, const float* __restrict__ bgq,
               const float* __restrict__ gk, const float* __restrict__ bgk,
               const float* __restrict__ gv, const float* __restrict__ bgv,
               u16* __restrict__ qo, u16* __restrict__ ko, u16* __restrict__ vto,
               float* __restrict__ out)
{
  __shared__ u16 xs[64 * 128];           // 16 KB, swizzled
  const int bx = blockIdx.x;
  const int xcd = bx & 7, i = bx >> 3;
  const int tile = xcd * 32 + (i & 31);  // 0..255
  const int p = i >> 5;                  // 0..2
  const int rowbase = tile * 64;
  const int t = threadIdx.x;

  {
    const int row = t >> 2, seg = t & 3;
    const float4* src = (const float4*)(x + (size_t)(rowbase + row) * 128 + seg * 32);
    float4 f[8];
#pragma unroll
    for (int q = 0; q < 8; ++q) f[q] = src[q];
    if ((p == 0 && seg < 2) || (p == 1 && seg >= 2)) {
      float4* dst = (float4*)(out + (size_t)(rowbase + row) * 192 + seg * 32);
#pragma unroll
      for (int q = 0; q < 8; ++q) dst[q] = f[q];
    }
    const int base = row * 256 + seg * 64;
    const int swz = (row & 7) << 4;
    char* xb = (char*)xs;
#pragma unroll
    for (int q = 0; q < 4; ++q) {
      uint4 u;
      u.x = pk2(f[2 * q].x, f[2 * q].y);
      u.y = pk2(f[2 * q].z, f[2 * q].w);
      u.z = pk2(f[2 * q + 1].x, f[2 * q + 1].y);
      u.w = pk2(f[2 * q + 1].z, f[2 * q + 1].w);
      *(uint4*)(xb + ((base + 16 * q) ^ swz)) = u;
    }
  }

  const int w = t >> 6, l = t & 63, lg = l >> 4, l15 = l & 15;
  U8 bfr[4][4];
  const u16* wp = wf + (size_t)p * (16 * 64 * 8);
#pragma unroll
  for (int s = 0; s < 4; ++s)
#pragma unroll
    for (int nt = 0; nt < 4; ++nt)
      bfr[s][nt].u4 = *(const uint4*)(wp + ((s * 4 + nt) * 64 + l) * 8);

  __syncthreads();

  f32x4 acc[4];
#pragma unroll
  for (int nt = 0; nt < 4; ++nt) acc[nt] = (f32x4){0.f, 0.f, 0.f, 0.f};
  const int abase = (16 * w + l15) * 256;
  const int aswz = (l15 & 7) << 4;
  const char* xb = (const char*)xs;
#pragma unroll
  for (int s = 0; s < 4; ++s) {
    U8 af;
    af.q[0] = *(const uint2*)(xb + ((abase + s * 64 + 8 * lg) ^ aswz));
    af.q[1] = *(const uint2*)(xb + ((abase + s * 64 + 8 * lg + 32) ^ aswz));
#pragma unroll
    for (int nt = 0; nt < 4; ++nt)
      acc[nt] = __builtin_amdgcn_mfma_f32_16x16x32_bf16(af.v, bfr[s][nt].v, acc[nt], 0, 0, 0);
  }

  const float* bb = (p == 0) ? bq : (p == 1) ? bk : bv;
  const float* gg = (p == 0) ? gq : (p == 1) ? gk : gv;
  const float* hh = (p == 0) ? bgq : (p == 1) ? bgk : bgv;
  float bcol[4], gcol[4], hcol[4];
#pragma unroll
  for (int nt = 0; nt < 4; ++nt) {
    int col = l15 + 16 * nt;
    bcol[nt] = bb[col]; gcol[nt] = gg[col]; hcol[nt] = hh[col];
  }
  float vals[4][4];
#pragma unroll
  for (int nt = 0; nt < 4; ++nt)
#pragma unroll
    for (int r = 0; r < 4; ++r) vals[nt][r] = acc[nt][r] + bcol[nt];

  float s1[4], s2[4];
#pragma unroll
  for (int r = 0; r < 4; ++r) {
    s1[r] = vals[0][r] + vals[1][r] + vals[2][r] + vals[3][r];
    s2[r] = vals[0][r] * vals[0][r] + vals[1][r] * vals[1][r]
          + vals[2][r] * vals[2][r] + vals[3][r] * vals[3][r];
#pragma unroll
    for (int d = 1; d < 16; d <<= 1) {
      s1[r] += __shfl_xor(s1[r], d);
      s2[r] += __shfl_xor(s2[r], d);
    }
  }

  if (p < 2) {
    u16* dst = (p == 0) ? qo : ko;
#pragma unroll
    for (int r = 0; r < 4; ++r) {
      float mu = s1[r] * (1.f / 64.f);
      float var = s2[r] * (1.f / 64.f) - mu * mu;
      float rs = rsqrtf(var + 1e-5f);
      int grow = rowbase + 16 * w + 4 * lg + r;
#pragma unroll
      for (int nt = 0; nt < 4; ++nt)
        dst[(size_t)grow * 64 + l15 + 16 * nt] =
            f2bf((vals[nt][r] - mu) * rs * gcol[nt] + hcol[nt]);
    }
  } else {
    const int b = rowbase >> 12;
    const int tl0 = (rowbase & 4095) + 16 * w + 4 * lg;
#pragma unroll
    for (int r = 0; r < 4; ++r) {
      float mu = s1[r] * (1.f / 64.f);
      float var = s2[r] * (1.f / 64.f) - mu * mu;
      float rs = rsqrtf(var + 1e-5f);
#pragma unroll
      for (int nt = 0; nt < 4; ++nt)
        vto[(size_t)(b * 64 + l15 + 16 * nt) * TT + tl0 + r] =
            f2bf((vals[nt][r] - mu) * rs * gcol[nt] + hcol[nt]);
    }
  }
}

// ---------------------------------------------------------------------------
// Kernel 2a: causal flash attention, W-way balanced key-split.
// qtile q (64 rows) has ns(q)=(q>>log2W)+1 segments; segment s covers KV
// tiles [s*W, min(s*W+W, q+1)) -> every block <= W iterations.
// Band math: band Q=q>>log2W starts at flat index (W/2)*Q*(Q+1).
// T14 prefetch: next tile's global loads issued under current compute.
// Partials: (m,l) f32 + pre-normalized acc bf16.
// ---------------------------------------------------------------------------
__global__ __launch_bounds__(256)
void attn_splitW(const u16* __restrict__ qg, const u16* __restrict__ kg,
                 const u16* __restrict__ vtg,
                 float* __restrict__ mP, float* __restrict__ lP,
                 u16* __restrict__ aP,
                 int Wseg, int maxseg, int halfcnt)
{
  __shared__ u16 kl[64 * 64];
  __shared__ u16 vl[64 * 64];
  const int bx = blockIdx.x;
  const int xcd = bx & 7, b = xcd >> 1, e = xcd & 1;
  const int j = e * halfcnt + (bx >> 3);
  const int Wh = Wseg >> 1;
  int Q = 0;
  while (Wh * (Q + 1) * (Q + 2) <= j) ++Q;
  const int ip = j - Wh * Q * (Q + 1);
  const int dv = ip / (Q + 1);
  const int q = Wseg * Q + dv;
  const int s = ip - dv * (Q + 1);
  const int q0 = q * 64;
  const int tileid = b * 64 + q;
  const int it0 = s * Wseg;
  const int it1 = min(it0 + Wseg, q + 1);

  const int t = threadIdx.x;
  const int w = t >> 6, l = t & 63;
  const int l15 = l & 15, lg = l >> 4;
  const int swzl = (l15 & 7) << 4;

  const int qrow = q0 + 16 * w + l15;
  const u16* qrp = qg + (size_t)(b * TT + qrow) * 64;
  U8 qf[2];
#pragma unroll
  for (int hh = 0; hh < 2; ++hh) {
    qf[hh].q[0] = *(const uint2*)(qrp + 32 * hh + 4 * lg);
    qf[hh].q[1] = *(const uint2*)(qrp + 32 * hh + 4 * lg + 16);
  }

  // staging geometry + prefetch regs
  const int key = t >> 2;
  const int part = t & 3;
  const int sbase = key * 128 + part * 32;
  const int ssw = (key & 7) << 4;
  uint4 kr0, kr1, vr0, vr1;
  {
    const u16* ks = kg + (size_t)(b * TT + it0 * 64 + key) * 64 + part * 16;
    kr0 = ((const uint4*)ks)[0];
    kr1 = ((const uint4*)ks)[1];
    const u16* vs = vtg + (size_t)(b * 64 + key) * TT + it0 * 64 + part * 16;
    vr0 = ((const uint4*)vs)[0];
    vr1 = ((const uint4*)vs)[1];
  }

  float m_run = -1e30f, l_run = 0.f;
  f32x4 acc[4];
#pragma unroll
  for (int ct = 0; ct < 4; ++ct) acc[ct] = (f32x4){0.f, 0.f, 0.f, 0.f};

  for (int it = it0; it < it1; ++it) {
    const int kb = it * 64;
    // ---- write prefetched tile to LDS ----
    {
      char* kd = (char*)kl;
      char* vd = (char*)vl;
      *(uint4*)(kd + ((sbase + 0) ^ ssw)) = kr0;
      *(uint4*)(kd + ((sbase + 16) ^ ssw)) = kr1;
      *(uint4*)(vd + ((sbase + 0) ^ ssw)) = vr0;
      *(uint4*)(vd + ((sbase + 16) ^ ssw)) = vr1;
    }
    __syncthreads();
    // ---- issue next tile's global loads (hidden under compute) ----
    if (it + 1 < it1) {
      const u16* ks = kg + (size_t)(b * TT + (it + 1) * 64 + key) * 64 + part * 16;
      kr0 = ((const uint4*)ks)[0];
      kr1 = ((const uint4*)ks)[1];
      const u16* vs = vtg + (size_t)(b * 64 + key) * TT + (it + 1) * 64 + part * 16;
      vr0 = ((const uint4*)vs)[0];
      vr1 = ((const uint4*)vs)[1];
    }

    // ---- S^T = K * Q^T ----
    f32x4 st[4];
#pragma unroll
    for (int t4 = 0; t4 < 4; ++t4) {
      const int rbase = (16 * t4 + l15) * 128 + 8 * lg;
      const char* kp = (const char*)kl;
      U8 kf0, kf1;
      kf0.q[0] = *(const uint2*)(kp + ((rbase + 0) ^ swzl));
      kf0.q[1] = *(const uint2*)(kp + ((rbase + 32) ^ swzl));
      kf1.q[0] = *(const uint2*)(kp + ((rbase + 64) ^ swzl));
      kf1.q[1] = *(const uint2*)(kp + ((rbase + 96) ^ swzl));
      f32x4 d = {0.f, 0.f, 0.f, 0.f};
      d = __builtin_amdgcn_mfma_f32_16x16x32_bf16(kf0.v, qf[0].v, d, 0, 0, 0);
      d = __builtin_amdgcn_mfma_f32_16x16x32_bf16(kf1.v, qf[1].v, d, 0, 0, 0);
      st[t4] = d;
    }

    // ---- online softmax ----
    float sv[16];
    const bool needmask = (kb + 63 > q0 + 16 * w);
#pragma unroll
    for (int t4 = 0; t4 < 4; ++t4) {
#pragma unroll
      for (int r = 0; r < 4; ++r) {
        float sc = st[t4][r] * 0.125f;
        if (needmask) {
          int keyidx = kb + 16 * t4 + 4 * lg + r;
          if (keyidx > qrow) sc = -1e30f;
        }
        sv[t4 * 4 + r] = sc;
      }
    }
    float mt = sv[0];
#pragma unroll
    for (int i = 1; i < 16; ++i) mt = fmaxf(mt, sv[i]);
    mt = fmaxf(mt, __shfl_xor(mt, 16));
    mt = fmaxf(mt, __shfl_xor(mt, 32));
    const float mnew = fmaxf(m_run, mt);
    const float al = __expf(m_run - mnew);
    float pv[16];
    float rsum = 0.f;
#pragma unroll
    for (int i = 0; i < 16; ++i) { pv[i] = __expf(sv[i] - mnew); rsum += pv[i]; }
    rsum += __shfl_xor(rsum, 16);
    rsum += __shfl_xor(rsum, 32);
    l_run = l_run * al + rsum;
    m_run = mnew;
    float ar[4];
#pragma unroll
    for (int r = 0; r < 4; ++r) ar[r] = __shfl(al, 4 * lg + r);
#pragma unroll
    for (int ct = 0; ct < 4; ++ct) {
#pragma unroll
      for (int r = 0; r < 4; ++r) acc[ct][r] *= ar[r];
    }
    U8 pa[2];
#pragma unroll
    for (int u = 0; u < 2; ++u) {
#pragma unroll
      for (int i = 0; i < 8; ++i) pa[u].s[i] = (short)f2bf(pv[8 * u + i]);
    }

    // ---- acc += P * V ----
#pragma unroll
    for (int ct = 0; ct < 4; ++ct) {
      const int vb = (16 * ct + l15) * 128 + 8 * lg;
      const char* vp = (const char*)vl;
#pragma unroll
      for (int u = 0; u < 2; ++u) {
        U8 vf;
        vf.q[0] = *(const uint2*)(vp + ((vb + 64 * u + 0) ^ swzl));
        vf.q[1] = *(const uint2*)(vp + ((vb + 64 * u + 32) ^ swzl));
        acc[ct] = __builtin_amdgcn_mfma_f32_16x16x32_bf16(pa[u].v, vf.v, acc[ct], 0, 0, 0);
      }
    }
    __syncthreads();
  }

  // ---- write partials ----
  const size_t pbase = (size_t)(tileid * maxseg + s) * 64;
  if (lg == 0) {
    mP[pbase + 16 * w + l15] = m_run;
    lP[pbase + 16 * w + l15] = l_run;
  }
#pragma unroll
  for (int ct = 0; ct < 4; ++ct) {
#pragma unroll
    for (int r = 0; r < 4; ++r) {
      int rin = 16 * w + 4 * lg + r;
      aP[(pbase + rin) * 64 + l15 + 16 * ct] = f2bf(acc[ct][r]);
    }
  }
}

// ---------------------------------------------------------------------------
// Kernel 2b: merge the key segments + output LayerNorm. Wave = one row.
// ---------------------------------------------------------------------------
__global__ __launch_bounds__(256)
void attn_mergeW(const float* __restrict__ mP, const float* __restrict__ lP,
                 const u16* __restrict__ aP,
                 const float* __restrict__ go, const float* __restrict__ bgo,
                 float* __restrict__ out, int jshift, int maxseg)
{
  const int t = threadIdx.x;
  const int w = t >> 6, c = t & 63;
  const int row = blockIdx.x * 4 + w;       // 0..16383
  const int tid2 = row >> 6, rin = row & 63;
  const int q = tid2 & 63;
  const int ns = (q >> jshift) + 1;

  float m = -1e30f, L = 0.f, o = 0.f;
  for (int s = 0; s < ns; ++s) {
    const size_t pbase = (size_t)(tid2 * maxseg + s) * 64;
    float ms = mP[pbase + rin];
    float ls = lP[pbase + rin];
    float a = bf2f(aP[(pbase + rin) * 64 + c]);
    float mn = fmaxf(m, ms);
    float w0 = __expf(m - mn), w1 = __expf(ms - mn);
    L = L * w0 + ls * w1;
    o = o * w0 + a * w1;
    m = mn;
  }
  o /= L;

  float s1 = o, s2 = o * o;
#pragma unroll
  for (int d = 1; d < 64; d <<= 1) {
    s1 += __shfl_xor(s1, d);
    s2 += __shfl_xor(s2, d);
  }
  float mu = s1 * (1.f / 64.f);
  float var = s2 * (1.f / 64.f) - mu * mu;
  float rs = rsqrtf(var + 1e-5f);
  out[(size_t)row * 192 + 128 + c] = (o - mu) * rs * go[c] + bgo[c];
}

// ---------------------------------------------------------------------------
// Kernel 2 fallback (ws too small for any split partials): proven attn.
// ---------------------------------------------------------------------------
__global__ __launch_bounds__(128)
void attn1(const u16* __restrict__ qg, const u16* __restrict__ kg,
           const u16* __restrict__ vtg,
           const float* __restrict__ go, const float* __restrict__ bgo,
           float* __restrict__ out)
{
  __shared__ u16 kl[64 * 64];
  __shared__ u16 vl[64 * 64];
  const int bx = blockIdx.x;
  const int tt = (bx < 256) ? bx : (767 - bx);
  const int b = tt >> 7;
  const int q0 = (tt & 127) * 32;
  const int tid = threadIdx.x;
  const int w = tid >> 6;
  const int l = tid & 63;
  const int l15 = l & 15;
  const int lg = l >> 4;
  const int swzl = (l15 & 7) << 4;

  const int qrow = q0 + 16 * w + l15;
  const u16* qrp = qg + (size_t)(b * TT + qrow) * 64;
  U8 qf[2];
#pragma unroll
  for (int h = 0; h < 2; ++h) {
    qf[h].q[0] = *(const uint2*)(qrp + 32 * h + 4 * lg);
    qf[h].q[1] = *(const uint2*)(qrp + 32 * h + 4 * lg + 16);
  }

  float m_run = -1e30f, l_run = 0.f;
  f32x4 acc[4];
#pragma unroll
  for (int ct = 0; ct < 4; ++ct) acc[ct] = (f32x4){0.f, 0.f, 0.f, 0.f};

  const int nkv = (q0 >> 6) + 1;
  for (int it = 0; it < nkv; ++it) {
    const int kb = it * 64;
    {
      const int key = tid >> 1;
      const int dh = (tid & 1) * 32;
      const u16* ks = kg + (size_t)(b * TT + kb + key) * 64 + dh;
      uint4 d0 = *(const uint4*)(ks + 0);
      uint4 d1 = *(const uint4*)(ks + 8);
      uint4 d2 = *(const uint4*)(ks + 16);
      uint4 d3 = *(const uint4*)(ks + 24);
      const int base = key * 128 + dh * 2;
      const int sw = (key & 7) << 4;
      char* kd = (char*)kl;
      *(uint4*)(kd + ((base + 0) ^ sw)) = d0;
      *(uint4*)(kd + ((base + 16) ^ sw)) = d1;
      *(uint4*)(kd + ((base + 32) ^ sw)) = d2;
      *(uint4*)(kd + ((base + 48) ^ sw)) = d3;
      const u16* vs = vtg + (size_t)(b * 64 + key) * TT + kb + dh;
      uint4 e0 = *(const uint4*)(vs + 0);
      uint4 e1 = *(const uint4*)(vs + 8);
      uint4 e2 = *(const uint4*)(vs + 16);
      uint4 e3 = *(const uint4*)(vs + 24);
      char* vd = (char*)vl;
      *(uint4*)(vd + ((base + 0) ^ sw)) = e0;
      *(uint4*)(vd + ((base + 16) ^ sw)) = e1;
      *(uint4*)(vd + ((base + 32) ^ sw)) = e2;
      *(uint4*)(vd + ((base + 48) ^ sw)) = e3;
    }
    __syncthreads();

    f32x4 st[4];
#pragma unroll
    for (int t4 = 0; t4 < 4; ++t4) {
      const int rbase = (16 * t4 + l15) * 128 + 8 * lg;
      const char* kp = (const char*)kl;
      U8 kf0, kf1;
      kf0.q[0] = *(const uint2*)(kp + ((rbase + 0) ^ swzl));
      kf0.q[1] = *(const uint2*)(kp + ((rbase + 32) ^ swzl));
      kf1.q[0] = *(const uint2*)(kp + ((rbase + 64) ^ swzl));
      kf1.q[1] = *(const uint2*)(kp + ((rbase + 96) ^ swzl));
      f32x4 d = {0.f, 0.f, 0.f, 0.f};
      d = __builtin_amdgcn_mfma_f32_16x16x32_bf16(kf0.v, qf[0].v, d, 0, 0, 0);
      d = __builtin_amdgcn_mfma_f32_16x16x32_bf16(kf1.v, qf[1].v, d, 0, 0, 0);
      st[t4] = d;
    }

    float sv[16];
    const bool needmask = (kb + 63 > q0 + 16 * w);
#pragma unroll
    for (int t4 = 0; t4 < 4; ++t4) {
#pragma unroll
      for (int r = 0; r < 4; ++r) {
        float sc = st[t4][r] * 0.125f;
        if (needmask) {
          int keyidx = kb + 16 * t4 + 4 * lg + r;
          if (keyidx > qrow) sc = -1e30f;
        }
        sv[t4 * 4 + r] = sc;
      }
    }
    float mt = sv[0];
#pragma unroll
    for (int i = 1; i < 16; ++i) mt = fmaxf(mt, sv[i]);
    mt = fmaxf(mt, __shfl_xor(mt, 16));
    mt = fmaxf(mt, __shfl_xor(mt, 32));
    const float mnew = fmaxf(m_run, mt);
    const float al = __expf(m_run - mnew);
    float p[16];
    float rsum = 0.f;
#pragma unroll
    for (int i = 0; i < 16; ++i) { p[i] = __expf(sv[i] - mnew); rsum += p[i]; }
    rsum += __shfl_xor(rsum, 16);
    rsum += __shfl_xor(rsum, 32);
    l_run = l_run * al + rsum;
    m_run = mnew;
    float ar[4];
#pragma unroll
    for (int r = 0; r < 4; ++r) ar[r] = __shfl(al, 4 * lg + r);
#pragma unroll
    for (int ct = 0; ct < 4; ++ct) {
#pragma unroll
      for (int r = 0; r < 4; ++r) acc[ct][r] *= ar[r];
    }
    U8 pa[2];
#pragma unroll
    for (int u = 0; u < 2; ++u) {
#pragma unroll
      for (int i = 0; i < 8; ++i) pa[u].s[i] = (short)f2bf(p[8 * u + i]);
    }

#pragma unroll
    for (int ct = 0; ct < 4; ++ct) {
      const int vb = (16 * ct + l15) * 128 + 8 * lg;
      const char* vp = (const char*)vl;
#pragma unroll
      for (int u = 0; u < 2; ++u) {
        U8 vf;
        vf.q[0] = *(const uint2*)(vp + ((vb + 64 * u + 0) ^ swzl));
        vf.q[1] = *(const uint2*)(vp + ((vb + 64 * u + 32) ^ swzl));
        acc[ct] = __builtin_amdgcn_mfma_f32_16x16x32_bf16(pa[u].v, vf.v, acc[ct], 0, 0, 0);
      }
    }
    __syncthreads();
  }

  float linv[4];
#pragma unroll
  for (int r = 0; r < 4; ++r) linv[r] = 1.f / __shfl(l_run, 4 * lg + r);
  float o[4][4];
#pragma unroll
  for (int ct = 0; ct < 4; ++ct) {
#pragma unroll
    for (int r = 0; r < 4; ++r) o[ct][r] = acc[ct][r] * linv[r];
  }
  float s1[4], s2[4];
#pragma unroll
  for (int r = 0; r < 4; ++r) {
    s1[r] = o[0][r] + o[1][r] + o[2][r] + o[3][r];
    s2[r] = o[0][r] * o[0][r] + o[1][r] * o[1][r] + o[2][r] * o[2][r] + o[3][r] * o[3][r];
#pragma unroll
    for (int d = 1; d < 16; d <<= 1) {
      s1[r] += __shfl_xor(s1[r], d);
      s2[r] += __shfl_xor(s2[r], d);
    }
  }
  float gov[4], bgv2[4];
#pragma unroll
  for (int ct = 0; ct < 4; ++ct) {
    gov[ct] = go[16 * ct + l15];
    bgv2[ct] = bgo[16 * ct + l15];
  }
#pragma unroll
  for (int r = 0; r < 4; ++r) {
    float mu = s1[r] * (1.f / 64.f);
    float var = s2[r] * (1.f / 64.f) - mu * mu;
    float rs = rsqrtf(var + 1e-5f);
    int row = q0 + 16 * w + 4 * lg + r;
    float* op = out + (size_t)(b * TT + row) * 192 + 128;
#pragma unroll
    for (int ct = 0; ct < 4; ++ct)
      op[16 * ct + l15] = (o[ct][r] - mu) * rs * gov[ct] + bgv2[ct];
  }
}

extern "C" void kernel_launch(void* const* d_in, const int* in_sizes, int n_in,
                              void* d_out, int out_size, void* d_ws, size_t ws_size,
                              hipStream_t stream) {
  (void)in_sizes; (void)n_in; (void)out_size;
  const float* x   = (const float*)d_in[0];
  const float* Wq  = (const float*)d_in[1];
  const float* bq  = (const float*)d_in[2];
  const float* Wk  = (const float*)d_in[3];
  const float* bk  = (const float*)d_in[4];
  const float* Wv  = (const float*)d_in[5];
  const float* bv  = (const float*)d_in[6];
  const float* gq  = (const float*)d_in[7];
  const float* bgq = (const float*)d_in[8];
  const float* gk  = (const float*)d_in[9];
  const float* bgk = (const float*)d_in[10];
  const float* gv  = (const float*)d_in[11];
  const float* bgv = (const float*)d_in[12];
  const float* go  = (const float*)d_in[13];
  const float* bgo = (const float*)d_in[14];
  float* out = (float*)d_out;

  // ws layout (bytes):
  //   0       q  (2 MB bf16)   | 2 MB  k (2 MB) | 4 MB vt (2 MB, [b][col][T])
  //   6 MB    Wfrag (48 KB, 64 KB slot)
  //   then split-K partials: mP, lP (f32), aP (bf16), sized per maxseg.
  char* wsb = (char*)d_ws;
  u16* qws  = (u16*)wsb;
  u16* kws  = (u16*)(wsb + (2u << 20));
  u16* vtws = (u16*)(wsb + (4u << 20));
  u16* wfr  = (u16*)(wsb + (6u << 20));
  const size_t OFF_MP = (6u << 20) + 65536;

  wpack<<<48, 64, 0, stream>>>(Wq, Wk, Wv, wfr);
  proj_mfma<<<768, 256, 0, stream>>>(x, wfr, bq, bk, bv,
                                     gq, bgq, gk, bgk, gv, bgv,
                                     qws, kws, vtws, out);

  // W=8: maxseg=8 -> mP/lP 512 KB each, aP 16 MB; NEED8 ~= 24.2 MB
  {
    const size_t MPS8 = 256u * 8 * 64 * 4;
    const size_t APS8 = 256u * 8 * 64 * 64 * 2;
    const size_t OFF_LP8 = OFF_MP + MPS8;
    const size_t OFF_AP8 = OFF_LP8 + MPS8;
    const size_t NEED8 = OFF_AP8 + APS8;
    const size_t MPS32 = 256u * 2 * 64 * 4;
    const size_t APS32 = 256u * 2 * 64 * 64 * 2;
    const size_t OFF_LP32 = OFF_MP + MPS32;
    const size_t OFF_AP32 = OFF_LP32 + MPS32;
    const size_t NEED32 = OFF_AP32 + APS32;

    if (ws_size >= NEED8) {
      float* mP = (float*)(wsb + OFF_MP);
      float* lP = (float*)(wsb + OFF_LP8);
      u16*   aP = (u16*)(wsb + OFF_AP8);
      attn_splitW<<<1152, 256, 0, stream>>>(qws, kws, vtws, mP, lP, aP, 8, 8, 144);
      attn_mergeW<<<4096, 256, 0, stream>>>(mP, lP, aP, go, bgo, out, 3, 8);
    } else if (ws_size >= NEED32) {
      float* mP = (float*)(wsb + OFF_MP);
      float* lP = (float*)(wsb + OFF_LP32);
      u16*   aP = (u16*)(wsb + OFF_AP32);
      attn_splitW<<<384, 256, 0, stream>>>(qws, kws, vtws, mP, lP, aP, 32, 2, 48);
      attn_mergeW<<<4096, 256, 0, stream>>>(mP, lP, aP, go, bgo, out, 5, 2);
    } else {
      attn1<<<512, 128, 0, stream>>>(qws, kws, vtws, go, bgo, out);
    }
  }
}